// Round 5
// baseline (1154.690 us; speedup 1.0000x reference)
//
#include <hip/hip_runtime.h>

typedef __attribute__((ext_vector_type(8))) short short8;
typedef __attribute__((ext_vector_type(4))) float f32x4;
typedef unsigned int uint;
typedef unsigned short ushort;

#define T_ 256
#define B_ 16
#define D_ 256
#define H_ 512
#define V_ 32000
#define GH 2048   /* 4*H */
#define SENT 0xFFFFFFFFu
#define NTILE (32u * 250u)

__device__ __forceinline__ ushort f2bf(float f) {
    uint u = __float_as_uint(f);
    u += 0x7FFFu + ((u >> 16) & 1u);
    return (ushort)(u >> 16);
}

__device__ __forceinline__ float fsig(float x) {
    return 1.0f / (1.0f + __expf(-x));
}

__device__ __forceinline__ float ftanh(float x) {
    float a = __expf(-2.0f * fabsf(x));
    float t = (1.0f - a) / (1.0f + a);
    return x >= 0.0f ? t : -t;
}

__device__ __forceinline__ void cvt4(const float* s, ushort* d) {
    float4 v = *(const float4*)s;
    ushort4 o;
    o.x = f2bf(v.x); o.y = f2bf(v.y); o.z = f2bf(v.z); o.w = f2bf(v.w);
    *(ushort4*)d = o;
}

__device__ __forceinline__ uint aload(const uint* p) {
    return __hip_atomic_load(p, __ATOMIC_RELAXED, __HIP_MEMORY_SCOPE_AGENT);
}

// ---------------------------------------------------------------- prep ----
__global__ void prep_convert(const float* __restrict__ Wih, const float* __restrict__ Whh,
                             const float* __restrict__ Wfc, const float* __restrict__ bih,
                             const float* __restrict__ bhh,
                             ushort* __restrict__ dWih, ushort* __restrict__ dWhh,
                             ushort* __restrict__ dWfc, float* __restrict__ bsum) {
    const long nA = (long)GH * D_ / 4;
    const long nB = (long)GH * H_ / 4;
    const long nC = (long)V_ * H_ / 4;
    const long nS = GH / 4;
    long i = (long)blockIdx.x * blockDim.x + threadIdx.x;
    if (i >= nA + nB + nC + nS) return;
    if (i < nA) {
        cvt4(Wih + i * 4, dWih + i * 4);
    } else if (i < nA + nB) {
        long j = i - nA;
        cvt4(Whh + j * 4, dWhh + j * 4);
    } else if (i < nA + nB + nC) {
        long j = i - nA - nB;
        cvt4(Wfc + j * 4, dWfc + j * 4);
    } else {
        long j = (i - nA - nB - nC) * 4;
        float4 a = *(const float4*)(bih + j);
        float4 b = *(const float4*)(bhh + j);
        float4 o;
        o.x = a.x + b.x; o.y = a.y + b.y; o.z = a.z + b.z; o.w = a.w + b.w;
        *(float4*)(bsum + j) = o;
    }
}

__global__ void prep_xseq(const float* __restrict__ images, const int* __restrict__ labels,
                          const float* __restrict__ embed, ushort* __restrict__ xseq) {
    int m = blockIdx.x;
    int l = threadIdx.x;
    int t = m >> 4, b = m & 15;
    const float* src = (t == 0) ? (images + b * D_) : (embed + (long)labels[m] * D_);
    cvt4(src + l * 4, xseq + (long)m * D_ + l * 4);
}

// ------------------------------------------------- 128x128 bf16 GEMM ------
// (x_gates only now)
template <int K>
__global__ __launch_bounds__(256) void gemm_bt(const ushort* __restrict__ A,
                                               const ushort* __restrict__ Bw,
                                               float* __restrict__ C,
                                               const float* __restrict__ bias,
                                               int ldc) {
    __shared__ ushort As[128 * 64];
    __shared__ ushort Bs[128 * 64];
    const int tid = threadIdx.x;
    const int lane = tid & 63;
    const int w = tid >> 6;
    const int wr = w >> 1, wc = w & 1;
    const long mBase = (long)blockIdx.x * 128;
    const long nBase = (long)blockIdx.y * 128;

    f32x4 acc[4][4];
#pragma unroll
    for (int i = 0; i < 4; ++i)
#pragma unroll
        for (int j = 0; j < 4; ++j) acc[i][j] = (f32x4){0.f, 0.f, 0.f, 0.f};

    const char* Ab = (const char*)A;
    const char* Bb = (const char*)Bw;

    for (int kk = 0; kk < K / 64; ++kk) {
#pragma unroll
        for (int it = 0; it < 4; ++it) {
            int c = w * 4 + it;
            int r = c * 8 + (lane >> 3);
            int sg = (lane & 7) ^ (r & 7);
            long aoff = (mBase + r) * (long)(K * 2) + kk * 128 + sg * 16;
            long boff = (nBase + r) * (long)(K * 2) + kk * 128 + sg * 16;
            __builtin_amdgcn_global_load_lds(
                (const __attribute__((address_space(1))) void*)(Ab + aoff),
                (__attribute__((address_space(3))) void*)((char*)As + c * 1024), 16, 0, 0);
            __builtin_amdgcn_global_load_lds(
                (const __attribute__((address_space(1))) void*)(Bb + boff),
                (__attribute__((address_space(3))) void*)((char*)Bs + c * 1024), 16, 0, 0);
        }
        __syncthreads();
#pragma unroll
        for (int k2 = 0; k2 < 2; ++k2) {
            short8 af[4], bfr[4];
#pragma unroll
            for (int mi = 0; mi < 4; ++mi) {
                int mrow = wr * 64 + mi * 16 + (lane & 15);
                int g = (k2 * 4 + (lane >> 4)) ^ (mrow & 7);
                af[mi] = *(const short8*)((const char*)As + mrow * 128 + g * 16);
            }
#pragma unroll
            for (int ni = 0; ni < 4; ++ni) {
                int nrow = wc * 64 + ni * 16 + (lane & 15);
                int g = (k2 * 4 + (lane >> 4)) ^ (nrow & 7);
                bfr[ni] = *(const short8*)((const char*)Bs + nrow * 128 + g * 16);
            }
#pragma unroll
            for (int mi = 0; mi < 4; ++mi)
#pragma unroll
                for (int ni = 0; ni < 4; ++ni)
                    acc[mi][ni] = __builtin_amdgcn_mfma_f32_16x16x32_bf16(
                        af[mi], bfr[ni], acc[mi][ni], 0, 0, 0);
        }
        __syncthreads();
    }
#pragma unroll
    for (int ni = 0; ni < 4; ++ni) {
        long col = nBase + wc * 64 + ni * 16 + (lane & 15);
        float bv = bias[col];
#pragma unroll
        for (int mi = 0; mi < 4; ++mi) {
            long row0 = mBase + wr * 64 + mi * 16 + ((lane >> 4) << 2);
#pragma unroll
            for (int rr = 0; rr < 4; ++rr)
                C[(row0 + rr) * (long)ldc + col] = acc[mi][ni][rr] + bv;
        }
    }
}

// ---------------------------------------------- fused scan + FC GEMM ------
// grid = 256 blocks (1/CU, all co-resident).
//   blocks 0..31  : LSTM scan (R3 structure, 2 barriers/step, direct hb write)
//   blocks 32..255: persistent FC workers, dynamic tile counter, m-major order.
// Cross-block data only via relaxed agent-scope atomics (MALL coherent).
// FC stripe validity: polling t_last=8m+7 fully implies all t<=t_last are
// MALL-visible (induction: a visible h(t) word from scan block g implies g's
// block-wide poll of h(t-1) completed at MALL).
__global__ __launch_bounds__(256) void fused_scan_fc(const ushort* __restrict__ Whh,
                                                     const float* __restrict__ xg,
                                                     ushort* __restrict__ hs,
                                                     const ushort* __restrict__ Wfc,
                                                     const float* __restrict__ bfc,
                                                     float* __restrict__ out,
                                                     uint* __restrict__ counter) {
    __shared__ union {
        struct { ushort Ws[64 * 512]; ushort hb[16 * 512]; float gb[4][16][16]; } s;
        struct { ushort As[128 * 64]; ushort Bs[128 * 64]; uint tileShare; } f;
    } u;

    const int tid = threadIdx.x;
    const int lane = tid & 63;
    const int w = tid >> 6;

    if (blockIdx.x < 32) {
        // ================= scan =================
        const int g = blockIdx.x;
#pragma unroll
        for (int j = 0; j < 16; ++j) {
            int gid = j * 256 + tid;
            int row = gid >> 6;
            int gcol = gid & 63;
            int srow = (row >> 4) * H_ + g * 16 + (row & 15);
            uint4 v = *(const uint4*)(Whh + (long)srow * H_ + gcol * 8);
            int dg = gcol ^ (row & 7);
            *(uint4*)((char*)u.s.Ws + row * 1024 + dg * 16) = v;
        }
        __syncthreads();

        const int b = tid >> 4;
        const int jj = tid & 15;
        float cst = 0.0f;

        for (int t = 0; t < T_; ++t) {
            long xb = ((long)t * B_ + b) * GH + g * 16 + jj;
            float gi = xg[xb];
            float gf = xg[xb + 512];
            float gg = xg[xb + 1024];
            float go = xg[xb + 1536];

            if (t > 0) {
                // poll h(t-1), skipping this block's own 8 dwords per row
                uint* hsrcU = (uint*)hs + ((long)(t - 1) * (B_ * H_)) / 2 + b * 256;
                uint vals[16];
#pragma unroll
                for (int j = 0; j < 16; ++j) {
                    int u2 = jj + j * 16;
                    vals[j] = ((u2 >> 3) == g) ? 0u : aload(hsrcU + u2);
                }
                int guard = 0;
                for (;;) {
                    int pend = 0;
#pragma unroll
                    for (int j = 0; j < 16; ++j) pend += (vals[j] == SENT) ? 1 : 0;
                    if (pend == 0 || ++guard > (1 << 20)) break;
#pragma unroll
                    for (int j = 0; j < 16; ++j)
                        if (vals[j] == SENT)
                            vals[j] = aload(hsrcU + jj + j * 16);
                }
                // scatter non-own words into swizzled hb
#pragma unroll
                for (int j = 0; j < 16; ++j) {
                    int u2 = jj + j * 16;
                    if ((u2 >> 3) != g) {
                        int gcol = u2 >> 2, sub = u2 & 3;
                        int dg = gcol ^ (b & 7);
                        *(uint*)((char*)u.s.hb + b * 1024 + dg * 16 + sub * 4) = vals[j];
                    }
                }
                __syncthreads();   // barrier 1
                // wave w computes gate-w 16x16 tile, K=512
                f32x4 acc0 = (f32x4){0.f, 0.f, 0.f, 0.f};
                f32x4 acc1 = (f32x4){0.f, 0.f, 0.f, 0.f};
                const int arow = lane & 15;
                const int brow = w * 16 + (lane & 15);
#pragma unroll
                for (int k0 = 0; k0 < 16; k0 += 2) {
                    int ga0 = (k0 * 4 + (lane >> 4)) ^ (arow & 7);
                    int gB0 = (k0 * 4 + (lane >> 4)) ^ (brow & 7);
                    int ga1 = ((k0 + 1) * 4 + (lane >> 4)) ^ (arow & 7);
                    int gB1 = ((k0 + 1) * 4 + (lane >> 4)) ^ (brow & 7);
                    short8 a0 = *(const short8*)((const char*)u.s.hb + arow * 1024 + ga0 * 16);
                    short8 b0 = *(const short8*)((const char*)u.s.Ws + brow * 1024 + gB0 * 16);
                    short8 a1 = *(const short8*)((const char*)u.s.hb + arow * 1024 + ga1 * 16);
                    short8 b1 = *(const short8*)((const char*)u.s.Ws + brow * 1024 + gB1 * 16);
                    acc0 = __builtin_amdgcn_mfma_f32_16x16x32_bf16(a0, b0, acc0, 0, 0, 0);
                    acc1 = __builtin_amdgcn_mfma_f32_16x16x32_bf16(a1, b1, acc1, 0, 0, 0);
                }
#pragma unroll
                for (int r = 0; r < 4; ++r)
                    u.s.gb[w][((lane >> 4) << 2) + r][lane & 15] = acc0[r] + acc1[r];
                __syncthreads();   // barrier 2
                gi += u.s.gb[0][b][jj];
                gf += u.s.gb[1][b][jj];
                gg += u.s.gb[2][b][jj];
                go += u.s.gb[3][b][jj];
            }
            // cell
            float ii = fsig(gi), ff = fsig(gf), oo = fsig(go), tg = ftanh(gg);
            cst = ff * cst + ii * tg;
            float hv = oo * ftanh(cst);
            ushort hbv = f2bf(hv);
            // direct own write into swizzled hb (after barrier2 -> no WAR race;
            // visible to all at next step's barrier1)
            {
                int colb = (g * 16 + jj) * 2;
                int gcol = colb >> 4;
                int dg = gcol ^ (b & 7);
                *(ushort*)((char*)u.s.hb + b * 1024 + dg * 16 + (colb & 15)) = hbv;
            }
            // publish pair (coalesced dword) to MALL
            uint hbits = (uint)hbv;
            uint pbits = (uint)__shfl_xor((int)hbits, 1);
            if ((jj & 1) == 0) {
                uint val = hbits | (pbits << 16);
                uint* dst = (uint*)hs + ((long)t * B_ + b) * (H_ / 2) + (g * 16 + jj) / 2;
                __hip_atomic_store(dst, val, __ATOMIC_RELAXED, __HIP_MEMORY_SCOPE_AGENT);
            }
        }
    } else {
        // ================= FC workers =================
        const int wr = w >> 1, wc = w & 1;
        const char* Bb = (const char*)Wfc;
        const uint* hsU = (const uint*)hs;
        int last_valid = -1;

        for (;;) {
            __syncthreads();                       // protect tileShare reuse
            if (tid == 0) u.f.tileShare = atomicAdd(counter, 1u);
            __syncthreads();
            uint tile = u.f.tileShare;
            if (tile >= NTILE) break;
            int m = (int)(tile / 250u);
            int n = (int)(tile % 250u);

            if (m > last_valid) {
                // validate stripe m: poll t_last = 8m+7 fully (implies stripe)
                uint* base = (uint*)hs + ((long)(m * 8 + 7) * (B_ * H_)) / 2 + (tid >> 4) * 256;
                const int c0 = tid & 15;
                uint vals[16];
#pragma unroll
                for (int j = 0; j < 16; ++j) vals[j] = aload(base + c0 + j * 16);
                int guard = 0;
                for (;;) {
                    int pend = 0;
#pragma unroll
                    for (int j = 0; j < 16; ++j) pend += (vals[j] == SENT) ? 1 : 0;
                    if (pend == 0 || ++guard > (1 << 17)) break;
                    // coarse backoff: keep MALL poll traffic off the scan path
                    __builtin_amdgcn_s_sleep(127);
                    __builtin_amdgcn_s_sleep(127);
#pragma unroll
                    for (int j = 0; j < 16; ++j)
                        if (vals[j] == SENT) vals[j] = aload(base + c0 + j * 16);
                }
                last_valid = m;
                __syncthreads();   // whole block validated before staging
            }

            const long mBase = (long)m * 128;
            const long nBase = (long)n * 128;
            f32x4 acc[4][4];
#pragma unroll
            for (int i = 0; i < 4; ++i)
#pragma unroll
                for (int j = 0; j < 4; ++j) acc[i][j] = (f32x4){0.f, 0.f, 0.f, 0.f};

            for (int kk = 0; kk < 8; ++kk) {
                // A: MALL-coherent atomic staging (swizzled), never normal loads
#pragma unroll
                for (int q = 0; q < 4; ++q) {
                    int gi2 = q * 256 + tid;       // granule 0..1023
                    int r = gi2 >> 3, lgr = gi2 & 7;
                    int sgr = lgr ^ (r & 7);
                    long src = (mBase + r) * (long)(H_ / 2) + kk * 32 + sgr * 4;
                    uint4 vv;
                    vv.x = aload(hsU + src + 0);
                    vv.y = aload(hsU + src + 1);
                    vv.z = aload(hsU + src + 2);
                    vv.w = aload(hsU + src + 3);
                    *(uint4*)((char*)u.f.As + gi2 * 16) = vv;
                }
                // B: global_load_lds (weights from prior dispatch -> safe)
#pragma unroll
                for (int it = 0; it < 4; ++it) {
                    int c = w * 4 + it;
                    int r = c * 8 + (lane >> 3);
                    int sg = (lane & 7) ^ (r & 7);
                    long boff = (nBase + r) * (long)(H_ * 2) + kk * 128 + sg * 16;
                    __builtin_amdgcn_global_load_lds(
                        (const __attribute__((address_space(1))) void*)(Bb + boff),
                        (__attribute__((address_space(3))) void*)((char*)u.f.Bs + c * 1024), 16, 0, 0);
                }
                __syncthreads();
#pragma unroll
                for (int k2 = 0; k2 < 2; ++k2) {
                    short8 af[4], bfr[4];
#pragma unroll
                    for (int mi = 0; mi < 4; ++mi) {
                        int mrow = wr * 64 + mi * 16 + (lane & 15);
                        int gg2 = (k2 * 4 + (lane >> 4)) ^ (mrow & 7);
                        af[mi] = *(const short8*)((const char*)u.f.As + mrow * 128 + gg2 * 16);
                    }
#pragma unroll
                    for (int ni = 0; ni < 4; ++ni) {
                        int nrow = wc * 64 + ni * 16 + (lane & 15);
                        int gg2 = (k2 * 4 + (lane >> 4)) ^ (nrow & 7);
                        bfr[ni] = *(const short8*)((const char*)u.f.Bs + nrow * 128 + gg2 * 16);
                    }
#pragma unroll
                    for (int mi = 0; mi < 4; ++mi)
#pragma unroll
                        for (int ni = 0; ni < 4; ++ni)
                            acc[mi][ni] = __builtin_amdgcn_mfma_f32_16x16x32_bf16(
                                af[mi], bfr[ni], acc[mi][ni], 0, 0, 0);
                }
                __syncthreads();
            }
            // epilogue
#pragma unroll
            for (int ni = 0; ni < 4; ++ni) {
                long col = nBase + wc * 64 + ni * 16 + (lane & 15);
                float bv = bfc[col];
#pragma unroll
                for (int mi = 0; mi < 4; ++mi) {
                    long row0 = mBase + wr * 64 + mi * 16 + ((lane >> 4) << 2);
#pragma unroll
                    for (int rr = 0; rr < 4; ++rr)
                        out[(row0 + rr) * (long)V_ + col] = acc[mi][ni][rr] + bv;
                }
            }
        }
    }
}

// ---------------------------------------------------------------- host ----
extern "C" void kernel_launch(void* const* d_in, const int* in_sizes, int n_in,
                              void* d_out, int out_size, void* d_ws, size_t ws_size,
                              hipStream_t stream) {
    const float* images = (const float*)d_in[0];
    const int* labels   = (const int*)d_in[1];
    const float* embed  = (const float*)d_in[2];
    const float* Wih    = (const float*)d_in[3];
    const float* Whh    = (const float*)d_in[4];
    const float* bih    = (const float*)d_in[5];
    const float* bhh    = (const float*)d_in[6];
    const float* Wfc    = (const float*)d_in[7];
    const float* bfc    = (const float*)d_in[8];
    float* out = (float*)d_out;

    char* p = (char*)d_ws;
    ushort* dWfc = (ushort*)p; p += (long)V_ * H_ * 2;
    ushort* dWih = (ushort*)p; p += (long)GH * D_ * 2;
    ushort* dWhh = (ushort*)p; p += (long)GH * H_ * 2;
    ushort* xseq = (ushort*)p; p += (long)T_ * B_ * D_ * 2;
    float* xg    = (float*)p;  p += (long)T_ * B_ * GH * 4;
    ushort* hs   = (ushort*)p; p += (long)T_ * B_ * H_ * 2;
    float* bsum  = (float*)p;  p += GH * 4;
    uint* counter = (uint*)p;  p += 256;

    hipMemsetAsync(hs, 0xFF, (size_t)T_ * B_ * H_ * 2, stream);
    hipMemsetAsync(counter, 0, sizeof(uint), stream);

    {
        long total = (long)GH * D_ / 4 + (long)GH * H_ / 4 + (long)V_ * H_ / 4 + GH / 4;
        int blocks = (int)((total + 255) / 256);
        prep_convert<<<blocks, 256, 0, stream>>>(Wih, Whh, Wfc, bih, bhh, dWih, dWhh, dWfc, bsum);
    }
    prep_xseq<<<T_ * B_, 64, 0, stream>>>(images, labels, embed, xseq);

    // x_gates: (4096 x 2048) = xseq (4096 x 256) * Wih^T + (b_ih+b_hh)
    gemm_bt<D_><<<dim3(32, 16), 256, 0, stream>>>(xseq, dWih, xg, bsum, GH);

    // fused: 32 scan blocks + 224 persistent FC workers
    fused_scan_fc<<<256, 256, 0, stream>>>(dWhh, xg, hs, dWfc, bfc, out, counter);
}

// Round 6
// 1140.508 us; speedup vs baseline: 1.0124x; 1.0124x over previous
//
#include <hip/hip_runtime.h>

typedef __attribute__((ext_vector_type(8))) short short8;
typedef __attribute__((ext_vector_type(4))) float f32x4;
typedef unsigned int uint;
typedef unsigned short ushort;

#define T_ 256
#define B_ 16
#define D_ 256
#define H_ 512
#define V_ 32000
#define GH 2048   /* 4*H */
#define SENT 0xFFFFFFFFu
#define NTILE (32u * 250u)

__device__ __forceinline__ ushort f2bf(float f) {
    uint u = __float_as_uint(f);
    u += 0x7FFFu + ((u >> 16) & 1u);
    return (ushort)(u >> 16);
}

__device__ __forceinline__ float fsig(float x) {
    return 1.0f / (1.0f + __expf(-x));
}

__device__ __forceinline__ float ftanh(float x) {
    float a = __expf(-2.0f * fabsf(x));
    float t = (1.0f - a) / (1.0f + a);
    return x >= 0.0f ? t : -t;
}

__device__ __forceinline__ void cvt4(const float* s, ushort* d) {
    float4 v = *(const float4*)s;
    ushort4 o;
    o.x = f2bf(v.x); o.y = f2bf(v.y); o.z = f2bf(v.z); o.w = f2bf(v.w);
    *(ushort4*)d = o;
}

__device__ __forceinline__ uint aload(const uint* p) {
    return __hip_atomic_load(p, __ATOMIC_RELAXED, __HIP_MEMORY_SCOPE_AGENT);
}

// ---------------------------------------------------------------- prep ----
__global__ void prep_convert(const float* __restrict__ Wih, const float* __restrict__ Whh,
                             const float* __restrict__ Wfc, const float* __restrict__ bih,
                             const float* __restrict__ bhh,
                             ushort* __restrict__ dWih, ushort* __restrict__ dWhh,
                             ushort* __restrict__ dWfc, float* __restrict__ bsum) {
    const long nA = (long)GH * D_ / 4;
    const long nB = (long)GH * H_ / 4;
    const long nC = (long)V_ * H_ / 4;
    const long nS = GH / 4;
    long i = (long)blockIdx.x * blockDim.x + threadIdx.x;
    if (i >= nA + nB + nC + nS) return;
    if (i < nA) {
        cvt4(Wih + i * 4, dWih + i * 4);
    } else if (i < nA + nB) {
        long j = i - nA;
        cvt4(Whh + j * 4, dWhh + j * 4);
    } else if (i < nA + nB + nC) {
        long j = i - nA - nB;
        cvt4(Wfc + j * 4, dWfc + j * 4);
    } else {
        long j = (i - nA - nB - nC) * 4;
        float4 a = *(const float4*)(bih + j);
        float4 b = *(const float4*)(bhh + j);
        float4 o;
        o.x = a.x + b.x; o.y = a.y + b.y; o.z = a.z + b.z; o.w = a.w + b.w;
        *(float4*)(bsum + j) = o;
    }
}

__global__ void prep_xseq(const float* __restrict__ images, const int* __restrict__ labels,
                          const float* __restrict__ embed, ushort* __restrict__ xseq) {
    int m = blockIdx.x;
    int l = threadIdx.x;
    int t = m >> 4, b = m & 15;
    const float* src = (t == 0) ? (images + b * D_) : (embed + (long)labels[m] * D_);
    cvt4(src + l * 4, xseq + (long)m * D_ + l * 4);
}

// ------------------------------------------------- 128x128 bf16 GEMM ------
// (x_gates only)
template <int K>
__global__ __launch_bounds__(256) void gemm_bt(const ushort* __restrict__ A,
                                               const ushort* __restrict__ Bw,
                                               float* __restrict__ C,
                                               const float* __restrict__ bias,
                                               int ldc) {
    __shared__ ushort As[128 * 64];
    __shared__ ushort Bs[128 * 64];
    const int tid = threadIdx.x;
    const int lane = tid & 63;
    const int w = tid >> 6;
    const int wr = w >> 1, wc = w & 1;
    const long mBase = (long)blockIdx.x * 128;
    const long nBase = (long)blockIdx.y * 128;

    f32x4 acc[4][4];
#pragma unroll
    for (int i = 0; i < 4; ++i)
#pragma unroll
        for (int j = 0; j < 4; ++j) acc[i][j] = (f32x4){0.f, 0.f, 0.f, 0.f};

    const char* Ab = (const char*)A;
    const char* Bb = (const char*)Bw;

    for (int kk = 0; kk < K / 64; ++kk) {
#pragma unroll
        for (int it = 0; it < 4; ++it) {
            int c = w * 4 + it;
            int r = c * 8 + (lane >> 3);
            int sg = (lane & 7) ^ (r & 7);
            long aoff = (mBase + r) * (long)(K * 2) + kk * 128 + sg * 16;
            long boff = (nBase + r) * (long)(K * 2) + kk * 128 + sg * 16;
            __builtin_amdgcn_global_load_lds(
                (const __attribute__((address_space(1))) void*)(Ab + aoff),
                (__attribute__((address_space(3))) void*)((char*)As + c * 1024), 16, 0, 0);
            __builtin_amdgcn_global_load_lds(
                (const __attribute__((address_space(1))) void*)(Bb + boff),
                (__attribute__((address_space(3))) void*)((char*)Bs + c * 1024), 16, 0, 0);
        }
        __syncthreads();
#pragma unroll
        for (int k2 = 0; k2 < 2; ++k2) {
            short8 af[4], bfr[4];
#pragma unroll
            for (int mi = 0; mi < 4; ++mi) {
                int mrow = wr * 64 + mi * 16 + (lane & 15);
                int g = (k2 * 4 + (lane >> 4)) ^ (mrow & 7);
                af[mi] = *(const short8*)((const char*)As + mrow * 128 + g * 16);
            }
#pragma unroll
            for (int ni = 0; ni < 4; ++ni) {
                int nrow = wc * 64 + ni * 16 + (lane & 15);
                int g = (k2 * 4 + (lane >> 4)) ^ (nrow & 7);
                bfr[ni] = *(const short8*)((const char*)Bs + nrow * 128 + g * 16);
            }
#pragma unroll
            for (int mi = 0; mi < 4; ++mi)
#pragma unroll
                for (int ni = 0; ni < 4; ++ni)
                    acc[mi][ni] = __builtin_amdgcn_mfma_f32_16x16x32_bf16(
                        af[mi], bfr[ni], acc[mi][ni], 0, 0, 0);
        }
        __syncthreads();
    }
#pragma unroll
    for (int ni = 0; ni < 4; ++ni) {
        long col = nBase + wc * 64 + ni * 16 + (lane & 15);
        float bv = bias[col];
#pragma unroll
        for (int mi = 0; mi < 4; ++mi) {
            long row0 = mBase + wr * 64 + mi * 16 + ((lane >> 4) << 2);
#pragma unroll
            for (int rr = 0; rr < 4; ++rr)
                C[(row0 + rr) * (long)ldc + col] = acc[mi][ni][rr] + bv;
        }
    }
}

// ---------------------------------------------- fused scan + FC GEMM ------
// grid = 256 (1 block/CU, co-resident).
//   blocks 0..31  : LSTM scan (R3 structure); join FC pool when done.
//   blocks 32..255: persistent FC workers, dynamic m-major tile counter.
// Stripe validity (induction through MALL): a visible h(t) word from scan
// block g implies g observed ALL of h(t-1). So stripe m (t<=8m+7) is valid
// once one word per scan-block of step t=8m+8 is non-sentinel (32 dwords).
// Last stripe: full poll of t=255. After validation, hs lines are complete at
// MALL and were never normal-accessed on this XCD this dispatch -> cached
// global_load_lds staging is coherent.
__global__ __launch_bounds__(256) void fused_scan_fc(const ushort* __restrict__ Whh,
                                                     const float* __restrict__ xg,
                                                     ushort* __restrict__ hs,
                                                     const ushort* __restrict__ Wfc,
                                                     const float* __restrict__ bfc,
                                                     float* __restrict__ out,
                                                     uint* __restrict__ counter) {
    __shared__ union {
        struct { ushort Ws[64 * 512]; ushort hb[16 * 512]; float gb[4][16][16]; } s;
        struct { ushort As[128 * 64]; ushort Bs[128 * 64]; uint tileShare; } f;
    } u;

    const int tid = threadIdx.x;
    const int lane = tid & 63;
    const int w = tid >> 6;

    if (blockIdx.x < 32) {
        // ================= scan =================
        const int g = blockIdx.x;
#pragma unroll
        for (int j = 0; j < 16; ++j) {
            int gid = j * 256 + tid;
            int row = gid >> 6;
            int gcol = gid & 63;
            int srow = (row >> 4) * H_ + g * 16 + (row & 15);
            uint4 v = *(const uint4*)(Whh + (long)srow * H_ + gcol * 8);
            int dg = gcol ^ (row & 7);
            *(uint4*)((char*)u.s.Ws + row * 1024 + dg * 16) = v;
        }
        __syncthreads();

        const int b = tid >> 4;
        const int jj = tid & 15;
        float cst = 0.0f;

        for (int t = 0; t < T_; ++t) {
            long xb = ((long)t * B_ + b) * GH + g * 16 + jj;
            float gi = xg[xb];
            float gf = xg[xb + 512];
            float gg = xg[xb + 1024];
            float go = xg[xb + 1536];

            if (t > 0) {
                // poll h(t-1), skipping this block's own 8 dwords per row
                uint* hsrcU = (uint*)hs + ((long)(t - 1) * (B_ * H_)) / 2 + b * 256;
                uint vals[16];
#pragma unroll
                for (int j = 0; j < 16; ++j) {
                    int u2 = jj + j * 16;
                    vals[j] = ((u2 >> 3) == g) ? 0u : aload(hsrcU + u2);
                }
                int guard = 0;
                for (;;) {
                    int pend = 0;
#pragma unroll
                    for (int j = 0; j < 16; ++j) pend += (vals[j] == SENT) ? 1 : 0;
                    if (pend == 0 || ++guard > (1 << 20)) break;
#pragma unroll
                    for (int j = 0; j < 16; ++j)
                        if (vals[j] == SENT)
                            vals[j] = aload(hsrcU + jj + j * 16);
                }
                // scatter non-own words into swizzled hb
#pragma unroll
                for (int j = 0; j < 16; ++j) {
                    int u2 = jj + j * 16;
                    if ((u2 >> 3) != g) {
                        int gcol = u2 >> 2, sub = u2 & 3;
                        int dg = gcol ^ (b & 7);
                        *(uint*)((char*)u.s.hb + b * 1024 + dg * 16 + sub * 4) = vals[j];
                    }
                }
                __syncthreads();   // barrier 1
                f32x4 acc0 = (f32x4){0.f, 0.f, 0.f, 0.f};
                f32x4 acc1 = (f32x4){0.f, 0.f, 0.f, 0.f};
                const int arow = lane & 15;
                const int brow = w * 16 + (lane & 15);
#pragma unroll
                for (int k0 = 0; k0 < 16; k0 += 2) {
                    int ga0 = (k0 * 4 + (lane >> 4)) ^ (arow & 7);
                    int gB0 = (k0 * 4 + (lane >> 4)) ^ (brow & 7);
                    int ga1 = ((k0 + 1) * 4 + (lane >> 4)) ^ (arow & 7);
                    int gB1 = ((k0 + 1) * 4 + (lane >> 4)) ^ (brow & 7);
                    short8 a0 = *(const short8*)((const char*)u.s.hb + arow * 1024 + ga0 * 16);
                    short8 b0 = *(const short8*)((const char*)u.s.Ws + brow * 1024 + gB0 * 16);
                    short8 a1 = *(const short8*)((const char*)u.s.hb + arow * 1024 + ga1 * 16);
                    short8 b1 = *(const short8*)((const char*)u.s.Ws + brow * 1024 + gB1 * 16);
                    acc0 = __builtin_amdgcn_mfma_f32_16x16x32_bf16(a0, b0, acc0, 0, 0, 0);
                    acc1 = __builtin_amdgcn_mfma_f32_16x16x32_bf16(a1, b1, acc1, 0, 0, 0);
                }
#pragma unroll
                for (int r = 0; r < 4; ++r)
                    u.s.gb[w][((lane >> 4) << 2) + r][lane & 15] = acc0[r] + acc1[r];
                __syncthreads();   // barrier 2
                gi += u.s.gb[0][b][jj];
                gf += u.s.gb[1][b][jj];
                gg += u.s.gb[2][b][jj];
                go += u.s.gb[3][b][jj];
            }
            float ii = fsig(gi), ff = fsig(gf), oo = fsig(go), tg = ftanh(gg);
            cst = ff * cst + ii * tg;
            float hv = oo * ftanh(cst);
            ushort hbv = f2bf(hv);
            {
                int colb = (g * 16 + jj) * 2;
                int gcol = colb >> 4;
                int dg = gcol ^ (b & 7);
                *(ushort*)((char*)u.s.hb + b * 1024 + dg * 16 + (colb & 15)) = hbv;
            }
            uint hbits = (uint)hbv;
            uint pbits = (uint)__shfl_xor((int)hbits, 1);
            if ((jj & 1) == 0) {
                uint val = hbits | (pbits << 16);
                uint* dst = (uint*)hs + ((long)t * B_ + b) * (H_ / 2) + (g * 16 + jj) / 2;
                __hip_atomic_store(dst, val, __ATOMIC_RELAXED, __HIP_MEMORY_SCOPE_AGENT);
            }
        }
        // fall through: join the FC worker pool
    }

    // ================= FC workers (all blocks eventually) =================
    {
        const int wr = w >> 1, wc = w & 1;
        const char* Ab = (const char*)hs;
        const char* Bb = (const char*)Wfc;
        int last_valid = -1;

        for (;;) {
            __syncthreads();                       // protects tileShare reuse
            if (tid == 0) u.f.tileShare = atomicAdd(counter, 1u);
            __syncthreads();
            uint tile = u.f.tileShare;
            if (tile >= NTILE) break;
            int m = (int)(tile / 250u);
            int n = (int)(tile % 250u);

            if (m > last_valid) {
                if (m < 31) {
                    // poll one word per scan-block of step t=8m+8 (32 dwords)
                    if (tid < 32) {
                        const uint* pw = (const uint*)hs + (long)(m * 8 + 8) * (B_ * H_ / 2) + tid * 8;
                        int guard = 0;
                        while (aload(pw) == SENT) {
                            __builtin_amdgcn_s_sleep(8);
                            if (++guard > (1 << 18)) break;
                        }
                    }
                } else {
                    // last stripe: full poll of t=255 (16KB)
                    const uint* base = (const uint*)hs + (long)255 * (B_ * H_ / 2) + (tid >> 4) * 256;
                    const int c0 = tid & 15;
                    uint vals[16];
#pragma unroll
                    for (int j = 0; j < 16; ++j) vals[j] = aload(base + c0 + j * 16);
                    int guard = 0;
                    for (;;) {
                        int pend = 0;
#pragma unroll
                        for (int j = 0; j < 16; ++j) pend += (vals[j] == SENT) ? 1 : 0;
                        if (pend == 0 || ++guard > (1 << 16)) break;
                        __builtin_amdgcn_s_sleep(8);
#pragma unroll
                        for (int j = 0; j < 16; ++j)
                            if (vals[j] == SENT) vals[j] = aload(base + c0 + j * 16);
                    }
                }
                last_valid = m;
                __syncthreads();   // whole block gated before cached staging
            }

            const long mBase = (long)m * 128;
            const long nBase = (long)n * 128;
            f32x4 acc[4][4];
#pragma unroll
            for (int i = 0; i < 4; ++i)
#pragma unroll
                for (int j = 0; j < 4; ++j) acc[i][j] = (f32x4){0.f, 0.f, 0.f, 0.f};

            for (int kk = 0; kk < 8; ++kk) {
                // A (hs) and B (Wfc) both via cached global_load_lds
#pragma unroll
                for (int it = 0; it < 4; ++it) {
                    int c = w * 4 + it;
                    int r = c * 8 + (lane >> 3);
                    int sg = (lane & 7) ^ (r & 7);
                    long aoff = (mBase + r) * (long)(H_ * 2) + kk * 128 + sg * 16;
                    long boff = (nBase + r) * (long)(H_ * 2) + kk * 128 + sg * 16;
                    __builtin_amdgcn_global_load_lds(
                        (const __attribute__((address_space(1))) void*)(Ab + aoff),
                        (__attribute__((address_space(3))) void*)((char*)u.f.As + c * 1024), 16, 0, 0);
                    __builtin_amdgcn_global_load_lds(
                        (const __attribute__((address_space(1))) void*)(Bb + boff),
                        (__attribute__((address_space(3))) void*)((char*)u.f.Bs + c * 1024), 16, 0, 0);
                }
                __syncthreads();
#pragma unroll
                for (int k2 = 0; k2 < 2; ++k2) {
                    short8 af[4], bfr[4];
#pragma unroll
                    for (int mi = 0; mi < 4; ++mi) {
                        int mrow = wr * 64 + mi * 16 + (lane & 15);
                        int gg2 = (k2 * 4 + (lane >> 4)) ^ (mrow & 7);
                        af[mi] = *(const short8*)((const char*)u.f.As + mrow * 128 + gg2 * 16);
                    }
#pragma unroll
                    for (int ni = 0; ni < 4; ++ni) {
                        int nrow = wc * 64 + ni * 16 + (lane & 15);
                        int gg2 = (k2 * 4 + (lane >> 4)) ^ (nrow & 7);
                        bfr[ni] = *(const short8*)((const char*)u.f.Bs + nrow * 128 + gg2 * 16);
                    }
#pragma unroll
                    for (int mi = 0; mi < 4; ++mi)
#pragma unroll
                        for (int ni = 0; ni < 4; ++ni)
                            acc[mi][ni] = __builtin_amdgcn_mfma_f32_16x16x32_bf16(
                                af[mi], bfr[ni], acc[mi][ni], 0, 0, 0);
                }
                __syncthreads();
            }
#pragma unroll
            for (int ni = 0; ni < 4; ++ni) {
                long col = nBase + wc * 64 + ni * 16 + (lane & 15);
                float bv = bfc[col];
#pragma unroll
                for (int mi = 0; mi < 4; ++mi) {
                    long row0 = mBase + wr * 64 + mi * 16 + ((lane >> 4) << 2);
#pragma unroll
                    for (int rr = 0; rr < 4; ++rr)
                        out[(row0 + rr) * (long)V_ + col] = acc[mi][ni][rr] + bv;
                }
            }
        }
    }
}

// ---------------------------------------------------------------- host ----
extern "C" void kernel_launch(void* const* d_in, const int* in_sizes, int n_in,
                              void* d_out, int out_size, void* d_ws, size_t ws_size,
                              hipStream_t stream) {
    const float* images = (const float*)d_in[0];
    const int* labels   = (const int*)d_in[1];
    const float* embed  = (const float*)d_in[2];
    const float* Wih    = (const float*)d_in[3];
    const float* Whh    = (const float*)d_in[4];
    const float* bih    = (const float*)d_in[5];
    const float* bhh    = (const float*)d_in[6];
    const float* Wfc    = (const float*)d_in[7];
    const float* bfc    = (const float*)d_in[8];
    float* out = (float*)d_out;

    char* p = (char*)d_ws;
    ushort* dWfc = (ushort*)p; p += (long)V_ * H_ * 2;
    ushort* dWih = (ushort*)p; p += (long)GH * D_ * 2;
    ushort* dWhh = (ushort*)p; p += (long)GH * H_ * 2;
    ushort* xseq = (ushort*)p; p += (long)T_ * B_ * D_ * 2;
    float* xg    = (float*)p;  p += (long)T_ * B_ * GH * 4;
    ushort* hs   = (ushort*)p; p += (long)T_ * B_ * H_ * 2;
    float* bsum  = (float*)p;  p += GH * 4;
    uint* counter = (uint*)p;  p += 256;

    hipMemsetAsync(hs, 0xFF, (size_t)T_ * B_ * H_ * 2, stream);
    hipMemsetAsync(counter, 0, sizeof(uint), stream);

    {
        long total = (long)GH * D_ / 4 + (long)GH * H_ / 4 + (long)V_ * H_ / 4 + GH / 4;
        int blocks = (int)((total + 255) / 256);
        prep_convert<<<blocks, 256, 0, stream>>>(Wih, Whh, Wfc, bih, bhh, dWih, dWhh, dWfc, bsum);
    }
    prep_xseq<<<T_ * B_, 64, 0, stream>>>(images, labels, embed, xseq);

    // x_gates: (4096 x 2048) = xseq (4096 x 256) * Wih^T + (b_ih+b_hh)
    gemm_bt<D_><<<dim3(32, 16), 256, 0, stream>>>(xseq, dWih, xg, bsum, GH);

    // fused: 32 scan blocks + 224 persistent FC workers (+32 after scan)
    fused_scan_fc<<<256, 256, 0, stream>>>(dWhh, xg, hs, dWfc, bfc, out, counter);
}